// Round 9
// baseline (1272.988 us; speedup 1.0000x reference)
//
#include <hip/hip_runtime.h>
#include <hip/hip_cooperative_groups.h>

namespace cg = cooperative_groups;

#define U_CNT 100000
#define I_CNT 50000
#define D_DIM 64
#define N_NODES 150000            // U + I
#define CHUNK 4096                // edges per block(-iteration) in hist/scatter
#define NBKT 586                  // ceil(N_NODES/256) coarse buckets (256 nodes each)
#define CCAP 3584                 // LDS edge cache per bucket (fallback path)

// ---------- bf16 helpers ----------
__device__ __forceinline__ float blo(unsigned u) { return __uint_as_float(u << 16); }
__device__ __forceinline__ float bhi(unsigned u) { return __uint_as_float(u & 0xFFFF0000u); }
__device__ __forceinline__ unsigned f2b(float f) {  // fp32 -> bf16 bits, RNE
    unsigned b = __float_as_uint(f);
    return (b + 0x7FFFu + ((b >> 16) & 1u)) >> 16;
}
__device__ __forceinline__ unsigned pack2(float a, float b) {
    return f2b(a) | (f2b(b) << 16);
}

__device__ __forceinline__ void fma8(float (&acc)[8], float v, uint4 g) {
    acc[0] = fmaf(v, blo(g.x), acc[0]); acc[1] = fmaf(v, bhi(g.x), acc[1]);
    acc[2] = fmaf(v, blo(g.y), acc[2]); acc[3] = fmaf(v, bhi(g.y), acc[3]);
    acc[4] = fmaf(v, blo(g.z), acc[4]); acc[5] = fmaf(v, bhi(g.z), acc[5]);
    acc[6] = fmaf(v, blo(g.w), acc[6]); acc[7] = fmaf(v, bhi(g.w), acc[7]);
}

// ---------- shared SpMM body (both paths) ----------
template <int FINAL>
__device__ __forceinline__ void spmm_node(int node, int l,
                                          const int* __restrict__ row_ptr,
                                          const int2* __restrict__ csr,
                                          const uint4* __restrict__ ego_in,
                                          uint4* __restrict__ ego_out,
                                          const uint4* __restrict__ egoA,
                                          const uint4* __restrict__ egoB,
                                          float4* __restrict__ outp) {
    int beg = row_ptr[node];
    int end = row_ptr[node + 1];

    float a0[8] = {0, 0, 0, 0, 0, 0, 0, 0};
    float a1[8] = {0, 0, 0, 0, 0, 0, 0, 0};

    int2 e0 = csr[beg], e1 = csr[beg + 1], e2 = csr[beg + 2], e3 = csr[beg + 3];
    int j = beg;
    while (j + 4 <= end) {
        uint4 x0 = ego_in[(size_t)e0.x * 8 + l];
        uint4 x1 = ego_in[(size_t)e1.x * 8 + l];
        uint4 x2 = ego_in[(size_t)e2.x * 8 + l];
        uint4 x3 = ego_in[(size_t)e3.x * 8 + l];
        int2 n0 = csr[j + 4], n1 = csr[j + 5], n2 = csr[j + 6], n3 = csr[j + 7];
        fma8(a0, __int_as_float(e0.y), x0);
        fma8(a1, __int_as_float(e1.y), x1);
        fma8(a0, __int_as_float(e2.y), x2);
        fma8(a1, __int_as_float(e3.y), x3);
        e0 = n0; e1 = n1; e2 = n2; e3 = n3;
        j += 4;
    }
    int rem = end - j;  // 0..3
    if (rem > 0) fma8(a0, __int_as_float(e0.y), ego_in[(size_t)e0.x * 8 + l]);
    if (rem > 1) fma8(a1, __int_as_float(e1.y), ego_in[(size_t)e1.x * 8 + l]);
    if (rem > 2) fma8(a0, __int_as_float(e2.y), ego_in[(size_t)e2.x * 8 + l]);

    float acc[8];
#pragma unroll
    for (int k = 0; k < 8; ++k) acc[k] = a0[k] + a1[k];

    if (!FINAL) {
        uint4 r;
        r.x = pack2(acc[0], acc[1]); r.y = pack2(acc[2], acc[3]);
        r.z = pack2(acc[4], acc[5]); r.w = pack2(acc[6], acc[7]);
        ego_out[(size_t)node * 8 + l] = r;
    } else {
        uint4 a = egoA[(size_t)node * 8 + l];
        uint4 b = egoB[(size_t)node * 8 + l];
        const float s = 1.0f / 3.0f;
        float4 o0, o1;
        o0.x = (blo(a.x) + blo(b.x) + acc[0]) * s;
        o0.y = (bhi(a.x) + bhi(b.x) + acc[1]) * s;
        o0.z = (blo(a.y) + blo(b.y) + acc[2]) * s;
        o0.w = (bhi(a.y) + bhi(b.y) + acc[3]) * s;
        o1.x = (blo(a.z) + blo(b.z) + acc[4]) * s;
        o1.y = (bhi(a.z) + bhi(b.z) + acc[5]) * s;
        o1.z = (blo(a.w) + blo(b.w) + acc[6]) * s;
        o1.w = (bhi(a.w) + bhi(b.w) + acc[7]) * s;
        size_t ob = (size_t)node * 16 + 2 * l;
        outp[ob]     = o0;
        outp[ob + 1] = o1;
    }
}

// ============================================================================
// PATH 1: fused cooperative kernel (grid-stride, correct at ANY grid size)
// ============================================================================
__global__ __launch_bounds__(256, 4)
void fused_all(const int* __restrict__ src, const int* __restrict__ dst,
               const float* __restrict__ val, int nE,
               const float4* __restrict__ user4, const float4* __restrict__ item4,
               int n4u, int n4,
               int* __restrict__ bCnt, int* __restrict__ bCursor,
               int* __restrict__ bBase,
               uint2* __restrict__ tmp, int2* __restrict__ csr,
               int* __restrict__ row_ptr,
               uint4* __restrict__ ego0, uint4* __restrict__ ego_a,
               uint4* __restrict__ ego_b, float4* __restrict__ outp) {
    cg::grid_group grid = cg::this_grid();
    const int t = threadIdx.x;
    const int gtid = blockIdx.x * blockDim.x + t;
    const int gsz = gridDim.x * blockDim.x;
    const int NB_B = (nE + CHUNK - 1) / CHUNK;

    __shared__ int h[NBKT];
    __shared__ int scur[NBKT];
    __shared__ int fh[256];
    __shared__ int fscan[256];
    __shared__ int fcur[256];

    // ---- Phase Z: zero global counters ----
    for (int i = gtid; i < NBKT; i += gsz) { bCnt[i] = 0; bCursor[i] = 0; }
    __threadfence();
    grid.sync();

    // ---- Phase A: coarse histogram + fused fp32->bf16 convert ----
    for (int b = blockIdx.x; b < NB_B; b += gridDim.x) {
        for (int i = t; i < NBKT; i += 256) h[i] = 0;
        __syncthreads();
        int beg = b * CHUNK, end = min(nE, beg + CHUNK);
        for (int e = beg + t; e < end; e += 256)
            atomicAdd(&h[dst[e] >> 8], 1);
        __syncthreads();
        for (int i = t; i < NBKT; i += 256)
            if (h[i] > 0) atomicAdd(&bCnt[i], h[i]);
        __syncthreads();
    }
    for (int i = gtid; i < n4; i += gsz) {
        float4 f = (i < n4u) ? user4[i] : item4[i - n4u];
        ((uint2*)ego0)[i] = make_uint2(pack2(f.x, f.y), pack2(f.z, f.w));
    }
    __threadfence();
    grid.sync();

    // ---- Phase B: exclusive scan bCnt -> bBase (block 0, 256-wide chunks) ----
    if (blockIdx.x == 0) {
        int carry = 0;
        for (int c0 = 0; c0 < NBKT; c0 += 256) {
            int i = c0 + t;
            int v = (i < NBKT) ? bCnt[i] : 0;
            fscan[t] = v;
            __syncthreads();
            for (int off = 1; off < 256; off <<= 1) {
                int x = (t >= off) ? fscan[t - off] : 0;
                __syncthreads();
                fscan[t] += x;
                __syncthreads();
            }
            if (i < NBKT) bBase[i] = carry + fscan[t] - v;
            carry += fscan[255];
            __syncthreads();
        }
        if (t == 0) bBase[NBKT] = nE;
    }
    __threadfence();
    grid.sync();

    // ---- Phase C: scatter with global range reservation ----
    for (int b = blockIdx.x; b < NB_B; b += gridDim.x) {
        for (int i = t; i < NBKT; i += 256) h[i] = 0;
        __syncthreads();
        int beg = b * CHUNK, end = min(nE, beg + CHUNK);
        for (int e = beg + t; e < end; e += 256)
            atomicAdd(&h[dst[e] >> 8], 1);
        __syncthreads();
        for (int i = t; i < NBKT; i += 256) {
            int c = h[i];
            scur[i] = (c > 0) ? (bBase[i] + atomicAdd(&bCursor[i], c)) : 0;
        }
        __syncthreads();
        for (int e = beg + t; e < end; e += 256) {
            int d = dst[e];
            int pos = atomicAdd(&scur[d >> 8], 1);
            tmp[pos] = make_uint2((unsigned)src[e] | ((unsigned)(d & 255) << 18),
                                  __float_as_uint(val[e]));
        }
        __syncthreads();
    }
    __threadfence();
    grid.sync();

    // ---- Phase D: per-bucket fine sort -> csr + row_ptr ----
    for (int bkt = blockIdx.x; bkt < NBKT; bkt += gridDim.x) {
        int base = bBase[bkt];
        int endp = bBase[bkt + 1];
        int size = endp - base;
        int nbins = min(256, N_NODES - bkt * 256);
        fh[t] = 0;
        __syncthreads();
        for (int k = t; k < size; k += 256) {
            uint2 r = tmp[base + k];
            atomicAdd(&fh[(r.x >> 18) & 255], 1);
        }
        __syncthreads();
        int v = fh[t];
        fscan[t] = v;
        __syncthreads();
        for (int off = 1; off < 256; off <<= 1) {
            int x = (t >= off) ? fscan[t - off] : 0;
            __syncthreads();
            fscan[t] += x;
            __syncthreads();
        }
        int ex = fscan[t] - v;
        if (t < nbins) row_ptr[bkt * 256 + t] = base + ex;
        fcur[t] = ex;
        __syncthreads();
        if (bkt == NBKT - 1) {
            if (t == 0) row_ptr[N_NODES] = nE;
            if (t < 4)  csr[nE + t] = make_int2(0, 0);
        }
        for (int k = t; k < size; k += 256) {
            uint2 r = tmp[base + k];
            int f = (r.x >> 18) & 255;
            int p = atomicAdd(&fcur[f], 1);
            csr[base + p] = make_int2((int)(r.x & 0x3FFFFu), (int)r.y);
        }
        __syncthreads();
    }
    __threadfence();
    grid.sync();

    // ---- Phases E/F/G: 3 SpMM layers ----
    int l = gtid & 7;
    int ngrp = gsz >> 3;
    for (int node = gtid >> 3; node < N_NODES; node += ngrp)
        spmm_node<0>(node, l, row_ptr, csr, ego0, ego_a, nullptr, nullptr, nullptr);
    __threadfence();
    grid.sync();
    for (int node = gtid >> 3; node < N_NODES; node += ngrp)
        spmm_node<0>(node, l, row_ptr, csr, ego_a, ego_b, nullptr, nullptr, nullptr);
    __threadfence();
    grid.sync();
    for (int node = gtid >> 3; node < N_NODES; node += ngrp)
        spmm_node<1>(node, l, row_ptr, csr, ego_b, nullptr, ego_a, ego_b, outp);
}

// ============================================================================
// PATH 2: fallback — the R7 multi-kernel pipeline (verified 244.6 us)
// ============================================================================
__global__ void bucket_hist(const int* __restrict__ dst, int* __restrict__ bCnt,
                            int nE,
                            const float4* __restrict__ user4,
                            const float4* __restrict__ item4,
                            uint2* __restrict__ ego0, int n4u, int n4) {
    __shared__ int h[NBKT];
    for (int i = threadIdx.x; i < NBKT; i += blockDim.x) h[i] = 0;
    __syncthreads();
    int b = blockIdx.x;
    int beg = b * CHUNK, end = min(nE, beg + CHUNK);
    for (int e = beg + (int)threadIdx.x; e < end; e += blockDim.x)
        atomicAdd(&h[dst[e] >> 8], 1);
    __syncthreads();
    for (int i = threadIdx.x; i < NBKT; i += blockDim.x)
        if (h[i] > 0) atomicAdd(&bCnt[i], h[i]);
    int gsz = gridDim.x * blockDim.x;
    for (int i = blockIdx.x * blockDim.x + threadIdx.x; i < n4; i += gsz) {
        float4 f = (i < n4u) ? user4[i] : item4[i - n4u];
        ego0[i] = make_uint2(pack2(f.x, f.y), pack2(f.z, f.w));
    }
}

__global__ void scan586(const int* __restrict__ bCnt, int* __restrict__ bBase, int nE) {
    __shared__ int sm[1024];
    int t = threadIdx.x;
    int v = (t < NBKT) ? bCnt[t] : 0;
    sm[t] = v;
    __syncthreads();
    for (int off = 1; off < 1024; off <<= 1) {
        int x = (t >= off) ? sm[t - off] : 0;
        __syncthreads();
        sm[t] += x;
        __syncthreads();
    }
    if (t < NBKT) bBase[t] = sm[t] - v;
    if (t == 0) bBase[NBKT] = nE;
}

__global__ void bucket_scatter(const int* __restrict__ src, const int* __restrict__ dst,
                               const float* __restrict__ val,
                               const int* __restrict__ bBase, int* __restrict__ bCursor,
                               uint2* __restrict__ tmp, int nE) {
    __shared__ int cnt[NBKT];
    __shared__ int cur[NBKT];
    int b = blockIdx.x;
    for (int i = threadIdx.x; i < NBKT; i += blockDim.x) cnt[i] = 0;
    __syncthreads();
    int beg = b * CHUNK, end = min(nE, beg + CHUNK);
    for (int e = beg + (int)threadIdx.x; e < end; e += blockDim.x)
        atomicAdd(&cnt[dst[e] >> 8], 1);
    __syncthreads();
    for (int i = threadIdx.x; i < NBKT; i += blockDim.x) {
        int c = cnt[i];
        cur[i] = (c > 0) ? (bBase[i] + atomicAdd(&bCursor[i], c)) : 0;
    }
    __syncthreads();
    for (int e = beg + (int)threadIdx.x; e < end; e += blockDim.x) {
        int d = dst[e];
        int pos = atomicAdd(&cur[d >> 8], 1);
        tmp[pos] = make_uint2((unsigned)src[e] | ((unsigned)(d & 255) << 18),
                              __float_as_uint(val[e]));
    }
}

__global__ void bucket_build(const int* __restrict__ bBase, const uint2* __restrict__ tmp,
                             int2* __restrict__ csr, int* __restrict__ row_ptr,
                             int nE) {
    __shared__ int hist[256];
    __shared__ int scanbuf[256];
    __shared__ int cur[256];
    __shared__ uint2 cache[CCAP];
    int bkt  = blockIdx.x;
    int base = bBase[bkt];
    int endp = bBase[bkt + 1];
    int size = endp - base;
    int nbins = min(256, N_NODES - bkt * 256);
    int t = threadIdx.x;

    hist[t] = 0;
    __syncthreads();
    bool cached = (size <= CCAP);
    for (int k = t; k < size; k += blockDim.x) {
        uint2 r = tmp[base + k];
        if (cached) cache[k] = r;
        atomicAdd(&hist[(r.x >> 18) & 255], 1);
    }
    __syncthreads();
    int v = hist[t];
    scanbuf[t] = v;
    __syncthreads();
    for (int off = 1; off < 256; off <<= 1) {
        int x = (t >= off) ? scanbuf[t - off] : 0;
        __syncthreads();
        scanbuf[t] += x;
        __syncthreads();
    }
    int ex = scanbuf[t] - v;
    if (t < nbins) row_ptr[bkt * 256 + t] = base + ex;
    cur[t] = ex;
    __syncthreads();
    if (bkt == NBKT - 1) {
        if (t == 0) row_ptr[N_NODES] = nE;
        if (t < 4)  csr[nE + t] = make_int2(0, 0);
    }
    for (int k = t; k < size; k += blockDim.x) {
        uint2 r = cached ? cache[k] : tmp[base + k];
        int f = (r.x >> 18) & 255;
        int p = atomicAdd(&cur[f], 1);
        csr[base + p] = make_int2((int)(r.x & 0x3FFFFu), (int)r.y);
    }
}

template <int FINAL>
__global__ void lgcn_spmm(const int* __restrict__ row_ptr,
                          const int2* __restrict__ csr,
                          const uint4* __restrict__ ego_in,
                          uint4* __restrict__ ego_out,
                          const uint4* __restrict__ egoA,
                          const uint4* __restrict__ egoB,
                          float4* __restrict__ out) {
    int node = (blockIdx.x * blockDim.x + threadIdx.x) >> 3;
    int l    = threadIdx.x & 7;
    if (node >= N_NODES) return;
    spmm_node<FINAL>(node, l, row_ptr, csr, ego_in, ego_out, egoA, egoB, out);
}

static inline size_t align_up(size_t x, size_t a) { return (x + a - 1) & ~(a - 1); }

extern "C" void kernel_launch(void* const* d_in, const int* in_sizes, int n_in,
                              void* d_out, int out_size, void* d_ws, size_t ws_size,
                              hipStream_t stream) {
    const int* edge_src  = (const int*)d_in[2];
    const int* edge_dst  = (const int*)d_in[3];
    const float* edge_vals = (const float*)d_in[4];
    int nE = in_sizes[2];  // 2E = 1.2M

    const float4* user4 = (const float4*)d_in[0];
    const float4* item4 = (const float4*)d_in[1];
    float4* outp = (float4*)d_out;
    const size_t nd = (size_t)N_NODES * D_DIM;

    const int NB_B = (nE + CHUNK - 1) / CHUNK;  // 293

    // ---- ws layout (shared by both paths) ----
    size_t off = 0;
    char* base = (char*)d_ws;
    int2*  csr     = (int2*)(base + off);  off = align_up(off + (size_t)(nE + 4) * sizeof(int2), 256);
    int*   row_ptr = (int*)(base + off);   off = align_up(off + (size_t)(N_NODES + 1) * 4, 256);
    uint2* tmp     = (uint2*)(base + off); off = align_up(off + (size_t)nE * sizeof(uint2), 256);
    int*   bCnt    = (int*)(base + off);   off = align_up(off + (size_t)NBKT * 4, 256);
    int*   bCursor = (int*)(base + off);   off = align_up(off + (size_t)NBKT * 4, 256);
    int*   bBase   = (int*)(base + off);   off = align_up(off + (size_t)(NBKT + 1) * 4, 256);
    uint4* ego0    = (uint4*)(base + off); off = align_up(off + (size_t)N_NODES * 128, 256);
    uint4* ego_a   = (uint4*)(base + off); off = align_up(off + (size_t)N_NODES * 128, 256);
    uint4* ego_b   = (uint4*)(base + off); off = align_up(off + (size_t)N_NODES * 128, 256);

    int n4  = (int)(nd / 4);
    int n4u = U_CNT * D_DIM / 4;

    // ---- query cooperative capacity once; clamp grid to co-residable size ----
    static int coopGrid = -2;  // -2 = not yet queried, -1 = unusable
    if (coopGrid == -2) {
        int perCU = 0;
        hipError_t e1 = hipOccupancyMaxActiveBlocksPerMultiprocessor(
            &perCU, (const void*)fused_all, 256, 0);
        int dev = 0;
        hipGetDevice(&dev);
        int nCU = 0;
        hipError_t e2 = hipDeviceGetAttribute(&nCU, hipDeviceAttributeMultiprocessorCount, dev);
        if (e1 == hipSuccess && e2 == hipSuccess && perCU > 0 && nCU > 0) {
            long g = (long)perCU * nCU;
            coopGrid = (int)(g > 1024 ? 1024 : g);
        } else {
            coopGrid = -1;
        }
    }

    bool done = false;
    if (coopGrid > 0) {
        void* args[] = {
            (void*)&edge_src, (void*)&edge_dst, (void*)&edge_vals, (void*)&nE,
            (void*)&user4, (void*)&item4, (void*)&n4u, (void*)&n4,
            (void*)&bCnt, (void*)&bCursor, (void*)&bBase,
            (void*)&tmp, (void*)&csr, (void*)&row_ptr,
            (void*)&ego0, (void*)&ego_a, (void*)&ego_b, (void*)&outp
        };
        hipError_t st = hipLaunchCooperativeKernel((void*)fused_all, dim3(coopGrid),
                                                   dim3(256), args, 0, stream);
        if (st == hipSuccess) {
            done = true;
        } else {
            coopGrid = -1;  // don't retry on later calls
        }
    }

    if (!done) {
        // ---- fallback: R7 multi-kernel pipeline (proven correct/fast) ----
        const int block = 256;
        hipMemsetAsync(bCnt, 0, 2 * align_up((size_t)NBKT * 4, 256), stream);
        bucket_hist<<<NB_B, block, 0, stream>>>(edge_dst, bCnt, nE,
            user4, item4, (uint2*)ego0, n4u, n4);
        scan586<<<1, 1024, 0, stream>>>(bCnt, bBase, nE);
        bucket_scatter<<<NB_B, block, 0, stream>>>(edge_src, edge_dst, edge_vals,
                                                   bBase, bCursor, tmp, nE);
        bucket_build<<<NBKT, block, 0, stream>>>(bBase, tmp, csr, row_ptr, nE);

        const size_t threads = (size_t)N_NODES * 8;
        const int spmm_grid = (int)((threads + block - 1) / block);
        lgcn_spmm<0><<<spmm_grid, block, 0, stream>>>(
            row_ptr, csr, ego0, ego_a, nullptr, nullptr, nullptr);
        lgcn_spmm<0><<<spmm_grid, block, 0, stream>>>(
            row_ptr, csr, ego_a, ego_b, nullptr, nullptr, nullptr);
        lgcn_spmm<1><<<spmm_grid, block, 0, stream>>>(
            row_ptr, csr, ego_b, nullptr, ego_a, ego_b, outp);
    }
}

// Round 10
// 260.205 us; speedup vs baseline: 4.8922x; 4.8922x over previous
//
#include <hip/hip_runtime.h>

#define U_CNT 100000
#define I_CNT 50000
#define D_DIM 64
#define N_NODES 150000            // U + I
#define CHUNK 4096                // edges per block in passes A/B
#define NBKT 586                  // ceil(N_NODES/256) coarse buckets (256 nodes each)
#define CCAP 3584                 // LDS edge cache per bucket (max bucket ~3.4K)

// ---------- bf16 helpers ----------
__device__ __forceinline__ float blo(unsigned u) { return __uint_as_float(u << 16); }
__device__ __forceinline__ float bhi(unsigned u) { return __uint_as_float(u & 0xFFFF0000u); }
__device__ __forceinline__ unsigned f2b(float f) {  // fp32 -> bf16 bits, RNE
    unsigned b = __float_as_uint(f);
    return (b + 0x7FFFu + ((b >> 16) & 1u)) >> 16;
}
__device__ __forceinline__ unsigned pack2(float a, float b) {
    return f2b(a) | (f2b(b) << 16);
}

// ---------- non-temporal helpers (keep streaming csr/row_ptr out of L2) ----------
__device__ __forceinline__ int2 ldnt2(const int2* p) {
    const unsigned long long* q = reinterpret_cast<const unsigned long long*>(p);
    unsigned long long v = __builtin_nontemporal_load(q);
    int2 r;
    r.x = (int)(unsigned)(v & 0xFFFFFFFFull);
    r.y = (int)(unsigned)(v >> 32);
    return r;
}
__device__ __forceinline__ int ldnt(const int* p) {
    return __builtin_nontemporal_load(p);
}

// ---------- Pass A: coarse LDS histogram -> global bucket counts (+ fused convert) ----------
__global__ void bucket_hist(const int* __restrict__ dst, int* __restrict__ bCnt,
                            int nE,
                            const float4* __restrict__ user4,
                            const float4* __restrict__ item4,
                            uint2* __restrict__ ego0, int n4u, int n4) {
    __shared__ int h[NBKT];
    for (int i = threadIdx.x; i < NBKT; i += blockDim.x) h[i] = 0;
    __syncthreads();
    int b = blockIdx.x;
    int beg = b * CHUNK, end = min(nE, beg + CHUNK);
    for (int e = beg + (int)threadIdx.x; e < end; e += blockDim.x)
        atomicAdd(&h[dst[e] >> 8], 1);
    __syncthreads();
    for (int i = threadIdx.x; i < NBKT; i += blockDim.x)
        if (h[i] > 0) atomicAdd(&bCnt[i], h[i]);
    // fused streaming fp32->bf16 convert (independent work; this kernel is light)
    int gsz = gridDim.x * blockDim.x;
    for (int i = blockIdx.x * blockDim.x + threadIdx.x; i < n4; i += gsz) {
        float4 f = (i < n4u) ? user4[i] : item4[i - n4u];
        ego0[i] = make_uint2(pack2(f.x, f.y), pack2(f.z, f.w));
    }
}

// ---------- exclusive scan of 586 bucket counts (single block) ----------
__global__ void scan586(const int* __restrict__ bCnt, int* __restrict__ bBase, int nE) {
    __shared__ int sm[1024];
    int t = threadIdx.x;
    int v = (t < NBKT) ? bCnt[t] : 0;
    sm[t] = v;
    __syncthreads();
    for (int off = 1; off < 1024; off <<= 1) {
        int x = (t >= off) ? sm[t - off] : 0;
        __syncthreads();
        sm[t] += x;
        __syncthreads();
    }
    if (t < NBKT) bBase[t] = sm[t] - v;  // exclusive
    if (t == 0) bBase[NBKT] = nE;
}

// ---------- Pass B: two-pass scatter with global range reservation ----------
// record: x = src (18b) | finebin (8b) << 18 ; y = val bits
__global__ void bucket_scatter(const int* __restrict__ src, const int* __restrict__ dst,
                               const float* __restrict__ val,
                               const int* __restrict__ bBase, int* __restrict__ bCursor,
                               uint2* __restrict__ tmp, int nE) {
    __shared__ int cnt[NBKT];
    __shared__ int cur[NBKT];
    int b = blockIdx.x;
    for (int i = threadIdx.x; i < NBKT; i += blockDim.x) cnt[i] = 0;
    __syncthreads();
    int beg = b * CHUNK, end = min(nE, beg + CHUNK);
    for (int e = beg + (int)threadIdx.x; e < end; e += blockDim.x)
        atomicAdd(&cnt[dst[e] >> 8], 1);
    __syncthreads();
    for (int i = threadIdx.x; i < NBKT; i += blockDim.x) {
        int c = cnt[i];
        cur[i] = (c > 0) ? (bBase[i] + atomicAdd(&bCursor[i], c)) : 0;
    }
    __syncthreads();
    for (int e = beg + (int)threadIdx.x; e < end; e += blockDim.x) {
        int d = dst[e];
        int pos = atomicAdd(&cur[d >> 8], 1);
        tmp[pos] = make_uint2((unsigned)src[e] | ((unsigned)(d & 255) << 18),
                              __float_as_uint(val[e]));
    }
}

// ---------- Pass C: per-bucket fine sort -> csr + row_ptr ----------
__global__ void bucket_build(const int* __restrict__ bBase, const uint2* __restrict__ tmp,
                             int2* __restrict__ csr, int* __restrict__ row_ptr,
                             int nE) {
    __shared__ int hist[256];
    __shared__ int scanbuf[256];
    __shared__ int cur[256];
    __shared__ uint2 cache[CCAP];
    int bkt  = blockIdx.x;
    int base = bBase[bkt];
    int endp = bBase[bkt + 1];
    int size = endp - base;
    int nbins = min(256, N_NODES - bkt * 256);
    int t = threadIdx.x;

    hist[t] = 0;
    __syncthreads();
    bool cached = (size <= CCAP);
    for (int k = t; k < size; k += blockDim.x) {
        uint2 r = tmp[base + k];
        if (cached) cache[k] = r;
        atomicAdd(&hist[(r.x >> 18) & 255], 1);
    }
    __syncthreads();
    // inclusive scan (Hillis-Steele) -> exclusive per-thread
    int v = hist[t];
    scanbuf[t] = v;
    __syncthreads();
    for (int off = 1; off < 256; off <<= 1) {
        int x = (t >= off) ? scanbuf[t - off] : 0;
        __syncthreads();
        scanbuf[t] += x;
        __syncthreads();
    }
    int ex = scanbuf[t] - v;
    if (t < nbins) row_ptr[bkt * 256 + t] = base + ex;
    cur[t] = ex;
    __syncthreads();
    if (bkt == NBKT - 1) {
        if (t == 0) row_ptr[N_NODES] = nE;
        if (t < 4)  csr[nE + t] = make_int2(0, 0);  // spmm prefetch pad
    }
    for (int k = t; k < size; k += blockDim.x) {
        uint2 r = cached ? cache[k] : tmp[base + k];
        int f = (r.x >> 18) & 255;
        int p = atomicAdd(&cur[f], 1);
        csr[base + p] = make_int2((int)(r.x & 0x3FFFFu), (int)r.y);
    }
}

// ---------- gather SpMM: 8 lanes/node, 16 B (8 bf16) per lane ----------
// 42 us/layer gather wall (verified invariant across 5 structural variants).
// NT loads on csr/row_ptr keep the read-once streams from evicting ego lines
// out of the 4 MB per-XCD L2 (ego table = 19.2 MB, hit rate ~40%).
__device__ __forceinline__ void fma8(float (&acc)[8], float v, uint4 g) {
    acc[0] = fmaf(v, blo(g.x), acc[0]); acc[1] = fmaf(v, bhi(g.x), acc[1]);
    acc[2] = fmaf(v, blo(g.y), acc[2]); acc[3] = fmaf(v, bhi(g.y), acc[3]);
    acc[4] = fmaf(v, blo(g.z), acc[4]); acc[5] = fmaf(v, bhi(g.z), acc[5]);
    acc[6] = fmaf(v, blo(g.w), acc[6]); acc[7] = fmaf(v, bhi(g.w), acc[7]);
}

template <int FINAL>
__global__ void lgcn_spmm(const int* __restrict__ row_ptr,
                          const int2* __restrict__ csr,
                          const uint4* __restrict__ ego_in,
                          uint4* __restrict__ ego_out,
                          const uint4* __restrict__ egoA,
                          const uint4* __restrict__ egoB,
                          float4* __restrict__ out) {
    int node = (blockIdx.x * blockDim.x + threadIdx.x) >> 3;
    int l    = threadIdx.x & 7;
    if (node >= N_NODES) return;
    int beg = ldnt(&row_ptr[node]);
    int end = ldnt(&row_ptr[node + 1]);

    float a0[8] = {0, 0, 0, 0, 0, 0, 0, 0};
    float a1[8] = {0, 0, 0, 0, 0, 0, 0, 0};

    int2 e0 = ldnt2(&csr[beg]), e1 = ldnt2(&csr[beg + 1]);
    int2 e2 = ldnt2(&csr[beg + 2]), e3 = ldnt2(&csr[beg + 3]);
    int j = beg;
    while (j + 4 <= end) {
        uint4 x0 = ego_in[(size_t)e0.x * 8 + l];
        uint4 x1 = ego_in[(size_t)e1.x * 8 + l];
        uint4 x2 = ego_in[(size_t)e2.x * 8 + l];
        uint4 x3 = ego_in[(size_t)e3.x * 8 + l];
        int2 n0 = ldnt2(&csr[j + 4]), n1 = ldnt2(&csr[j + 5]);
        int2 n2 = ldnt2(&csr[j + 6]), n3 = ldnt2(&csr[j + 7]);
        fma8(a0, __int_as_float(e0.y), x0);
        fma8(a1, __int_as_float(e1.y), x1);
        fma8(a0, __int_as_float(e2.y), x2);
        fma8(a1, __int_as_float(e3.y), x3);
        e0 = n0; e1 = n1; e2 = n2; e3 = n3;
        j += 4;
    }
    int rem = end - j;  // 0..3
    if (rem > 0) fma8(a0, __int_as_float(e0.y), ego_in[(size_t)e0.x * 8 + l]);
    if (rem > 1) fma8(a1, __int_as_float(e1.y), ego_in[(size_t)e1.x * 8 + l]);
    if (rem > 2) fma8(a0, __int_as_float(e2.y), ego_in[(size_t)e2.x * 8 + l]);

    float acc[8];
#pragma unroll
    for (int k = 0; k < 8; ++k) acc[k] = a0[k] + a1[k];

    if (!FINAL) {
        uint4 r;
        r.x = pack2(acc[0], acc[1]); r.y = pack2(acc[2], acc[3]);
        r.z = pack2(acc[4], acc[5]); r.w = pack2(acc[6], acc[7]);
        ego_out[(size_t)node * 8 + l] = r;
    } else {
        uint4 a = egoA[(size_t)node * 8 + l];
        uint4 b = egoB[(size_t)node * 8 + l];
        const float s = 1.0f / 3.0f;
        float4 o0, o1;
        o0.x = (blo(a.x) + blo(b.x) + acc[0]) * s;
        o0.y = (bhi(a.x) + bhi(b.x) + acc[1]) * s;
        o0.z = (blo(a.y) + blo(b.y) + acc[2]) * s;
        o0.w = (bhi(a.y) + bhi(b.y) + acc[3]) * s;
        o1.x = (blo(a.z) + blo(b.z) + acc[4]) * s;
        o1.y = (bhi(a.z) + bhi(b.z) + acc[5]) * s;
        o1.z = (blo(a.w) + blo(b.w) + acc[6]) * s;
        o1.w = (bhi(a.w) + bhi(b.w) + acc[7]) * s;
        size_t ob = (size_t)node * 16 + 2 * l;
        out[ob]     = o0;
        out[ob + 1] = o1;
    }
}

static inline size_t align_up(size_t x, size_t a) { return (x + a - 1) & ~(a - 1); }

extern "C" void kernel_launch(void* const* d_in, const int* in_sizes, int n_in,
                              void* d_out, int out_size, void* d_ws, size_t ws_size,
                              hipStream_t stream) {
    const float* user_emb  = (const float*)d_in[0];
    const float* item_emb  = (const float*)d_in[1];
    const int*   edge_src  = (const int*)d_in[2];
    const int*   edge_dst  = (const int*)d_in[3];
    const float* edge_vals = (const float*)d_in[4];
    const int    nE        = in_sizes[2];  // 2E = 1.2M

    float* out = (float*)d_out;
    const size_t nd = (size_t)N_NODES * D_DIM;

    const int NB_B = (nE + CHUNK - 1) / CHUNK;  // 293

    // ---- ws layout ----
    size_t off = 0;
    char* base = (char*)d_ws;
    int2*  csr     = (int2*)(base + off);  off = align_up(off + (size_t)(nE + 4) * sizeof(int2), 256);
    int*   row_ptr = (int*)(base + off);   off = align_up(off + (size_t)(N_NODES + 1) * 4, 256);
    uint2* tmp     = (uint2*)(base + off); off = align_up(off + (size_t)nE * sizeof(uint2), 256);
    int*   bCnt    = (int*)(base + off);   off = align_up(off + (size_t)NBKT * 4, 256);
    int*   bCursor = (int*)(base + off);   off = align_up(off + (size_t)NBKT * 4, 256);
    int*   bBase   = (int*)(base + off);   off = align_up(off + (size_t)(NBKT + 1) * 4, 256);
    uint4* ego0    = (uint4*)(base + off); off = align_up(off + (size_t)N_NODES * 128, 256);
    uint4* ego_a   = (uint4*)(base + off); off = align_up(off + (size_t)N_NODES * 128, 256);
    uint4* ego_b   = (uint4*)(base + off); off = align_up(off + (size_t)N_NODES * 128, 256);

    const int block = 256;
    const int n4  = (int)(nd / 4);
    const int n4u = U_CNT * D_DIM / 4;

    // ---- CSR build: hist -> scan -> reserve+scatter -> fine sort ----
    hipMemsetAsync(bCnt, 0, 2 * align_up((size_t)NBKT * 4, 256), stream);  // bCnt + bCursor
    bucket_hist<<<NB_B, block, 0, stream>>>(edge_dst, bCnt, nE,
        (const float4*)user_emb, (const float4*)item_emb, (uint2*)ego0, n4u, n4);
    scan586<<<1, 1024, 0, stream>>>(bCnt, bBase, nE);
    bucket_scatter<<<NB_B, block, 0, stream>>>(edge_src, edge_dst, edge_vals,
                                               bBase, bCursor, tmp, nE);
    bucket_build<<<NBKT, block, 0, stream>>>(bBase, tmp, csr, row_ptr, nE);

    // ---- 3 SpMM layers (bf16 gather, 8 lanes/node, x4 unroll, NT csr stream) ----
    const size_t threads = (size_t)N_NODES * 8;
    const int spmm_grid = (int)((threads + block - 1) / block);

    lgcn_spmm<0><<<spmm_grid, block, 0, stream>>>(
        row_ptr, csr, ego0, ego_a, nullptr, nullptr, nullptr);
    lgcn_spmm<0><<<spmm_grid, block, 0, stream>>>(
        row_ptr, csr, ego_a, ego_b, nullptr, nullptr, nullptr);
    lgcn_spmm<1><<<spmm_grid, block, 0, stream>>>(
        row_ptr, csr, ego_b, nullptr, ego_a, ego_b, (float4*)out);
}

// Round 11
// 242.288 us; speedup vs baseline: 5.2540x; 1.0740x over previous
//
#include <hip/hip_runtime.h>

#define U_CNT 100000
#define I_CNT 50000
#define D_DIM 64
#define N_NODES 150000            // U + I
#define CHUNK 4096                // edges per block in passes A/B
#define NBKT 586                  // ceil(N_NODES/256) coarse buckets (256 nodes each)
#define CCAP 3584                 // LDS edge cache per bucket (max bucket ~3.4K)

// ---------- bf16 helpers ----------
__device__ __forceinline__ float blo(unsigned u) { return __uint_as_float(u << 16); }
__device__ __forceinline__ float bhi(unsigned u) { return __uint_as_float(u & 0xFFFF0000u); }
__device__ __forceinline__ unsigned f2b(float f) {  // fp32 -> bf16 bits, RNE
    unsigned b = __float_as_uint(f);
    return (b + 0x7FFFu + ((b >> 16) & 1u)) >> 16;
}
__device__ __forceinline__ unsigned pack2(float a, float b) {
    return f2b(a) | (f2b(b) << 16);
}

// ---------- Pass A: coarse LDS histogram -> global bucket counts (+ fused convert) ----------
__global__ void bucket_hist(const int* __restrict__ dst, int* __restrict__ bCnt,
                            int nE,
                            const float4* __restrict__ user4,
                            const float4* __restrict__ item4,
                            uint2* __restrict__ ego0, int n4u, int n4) {
    __shared__ int h[NBKT];
    for (int i = threadIdx.x; i < NBKT; i += blockDim.x) h[i] = 0;
    __syncthreads();
    int b = blockIdx.x;
    int beg = b * CHUNK, end = min(nE, beg + CHUNK);
    for (int e = beg + (int)threadIdx.x; e < end; e += blockDim.x)
        atomicAdd(&h[dst[e] >> 8], 1);
    __syncthreads();
    for (int i = threadIdx.x; i < NBKT; i += blockDim.x)
        if (h[i] > 0) atomicAdd(&bCnt[i], h[i]);
    // fused streaming fp32->bf16 convert (independent work; this kernel is light)
    int gsz = gridDim.x * blockDim.x;
    for (int i = blockIdx.x * blockDim.x + threadIdx.x; i < n4; i += gsz) {
        float4 f = (i < n4u) ? user4[i] : item4[i - n4u];
        ego0[i] = make_uint2(pack2(f.x, f.y), pack2(f.z, f.w));
    }
}

// ---------- exclusive scan of 586 bucket counts (single block) ----------
__global__ void scan586(const int* __restrict__ bCnt, int* __restrict__ bBase, int nE) {
    __shared__ int sm[1024];
    int t = threadIdx.x;
    int v = (t < NBKT) ? bCnt[t] : 0;
    sm[t] = v;
    __syncthreads();
    for (int off = 1; off < 1024; off <<= 1) {
        int x = (t >= off) ? sm[t - off] : 0;
        __syncthreads();
        sm[t] += x;
        __syncthreads();
    }
    if (t < NBKT) bBase[t] = sm[t] - v;  // exclusive
    if (t == 0) bBase[NBKT] = nE;
}

// ---------- Pass B: two-pass scatter with global range reservation ----------
// record: x = src (18b) | finebin (8b) << 18 ; y = val bits
__global__ void bucket_scatter(const int* __restrict__ src, const int* __restrict__ dst,
                               const float* __restrict__ val,
                               const int* __restrict__ bBase, int* __restrict__ bCursor,
                               uint2* __restrict__ tmp, int nE) {
    __shared__ int cnt[NBKT];
    __shared__ int cur[NBKT];
    int b = blockIdx.x;
    for (int i = threadIdx.x; i < NBKT; i += blockDim.x) cnt[i] = 0;
    __syncthreads();
    int beg = b * CHUNK, end = min(nE, beg + CHUNK);
    for (int e = beg + (int)threadIdx.x; e < end; e += blockDim.x)
        atomicAdd(&cnt[dst[e] >> 8], 1);
    __syncthreads();
    for (int i = threadIdx.x; i < NBKT; i += blockDim.x) {
        int c = cnt[i];
        cur[i] = (c > 0) ? (bBase[i] + atomicAdd(&bCursor[i], c)) : 0;
    }
    __syncthreads();
    for (int e = beg + (int)threadIdx.x; e < end; e += blockDim.x) {
        int d = dst[e];
        int pos = atomicAdd(&cur[d >> 8], 1);
        tmp[pos] = make_uint2((unsigned)src[e] | ((unsigned)(d & 255) << 18),
                              __float_as_uint(val[e]));
    }
}

// ---------- Pass C: per-bucket fine sort -> csr + row_ptr ----------
__global__ void bucket_build(const int* __restrict__ bBase, const uint2* __restrict__ tmp,
                             int2* __restrict__ csr, int* __restrict__ row_ptr,
                             int nE) {
    __shared__ int hist[256];
    __shared__ int scanbuf[256];
    __shared__ int cur[256];
    __shared__ uint2 cache[CCAP];
    int bkt  = blockIdx.x;
    int base = bBase[bkt];
    int endp = bBase[bkt + 1];
    int size = endp - base;
    int nbins = min(256, N_NODES - bkt * 256);
    int t = threadIdx.x;

    hist[t] = 0;
    __syncthreads();
    bool cached = (size <= CCAP);
    for (int k = t; k < size; k += blockDim.x) {
        uint2 r = tmp[base + k];
        if (cached) cache[k] = r;
        atomicAdd(&hist[(r.x >> 18) & 255], 1);
    }
    __syncthreads();
    // inclusive scan (Hillis-Steele) -> exclusive per-thread
    int v = hist[t];
    scanbuf[t] = v;
    __syncthreads();
    for (int off = 1; off < 256; off <<= 1) {
        int x = (t >= off) ? scanbuf[t - off] : 0;
        __syncthreads();
        scanbuf[t] += x;
        __syncthreads();
    }
    int ex = scanbuf[t] - v;
    if (t < nbins) row_ptr[bkt * 256 + t] = base + ex;
    cur[t] = ex;
    __syncthreads();
    if (bkt == NBKT - 1) {
        if (t == 0) row_ptr[N_NODES] = nE;
        if (t < 4)  csr[nE + t] = make_int2(0, 0);  // spmm prefetch pad
    }
    for (int k = t; k < size; k += blockDim.x) {
        uint2 r = cached ? cache[k] : tmp[base + k];
        int f = (r.x >> 18) & 255;
        int p = atomicAdd(&cur[f], 1);
        csr[base + p] = make_int2((int)(r.x & 0x3FFFFu), (int)r.y);
    }
}

// ---------- gather SpMM: 8 lanes/node, 16 B (8 bf16) per lane ----------
// The 42 us/layer gather wall: 1.2M random 128 B rows from a 19.2 MB table
// (4 MB per-XCD L2, ~40% hit) = ~1.44M L2-miss lines/layer at ~34 G lines/s.
// Verified invariant across: node order (R1/R2), wave balance (R1/R2), NPG
// batching (R3), row src-sort (R5), edge-parallel LDS accum (R6, 11x worse),
// coop fusion (R9, 6x worse), NT cache policy (R10, neutral/worse).
__device__ __forceinline__ void fma8(float (&acc)[8], float v, uint4 g) {
    acc[0] = fmaf(v, blo(g.x), acc[0]); acc[1] = fmaf(v, bhi(g.x), acc[1]);
    acc[2] = fmaf(v, blo(g.y), acc[2]); acc[3] = fmaf(v, bhi(g.y), acc[3]);
    acc[4] = fmaf(v, blo(g.z), acc[4]); acc[5] = fmaf(v, bhi(g.z), acc[5]);
    acc[6] = fmaf(v, blo(g.w), acc[6]); acc[7] = fmaf(v, bhi(g.w), acc[7]);
}

template <int FINAL>
__global__ void lgcn_spmm(const int* __restrict__ row_ptr,
                          const int2* __restrict__ csr,
                          const uint4* __restrict__ ego_in,
                          uint4* __restrict__ ego_out,
                          const uint4* __restrict__ egoA,
                          const uint4* __restrict__ egoB,
                          float4* __restrict__ out) {
    int node = (blockIdx.x * blockDim.x + threadIdx.x) >> 3;
    int l    = threadIdx.x & 7;
    if (node >= N_NODES) return;
    int beg = row_ptr[node];
    int end = row_ptr[node + 1];

    float a0[8] = {0, 0, 0, 0, 0, 0, 0, 0};
    float a1[8] = {0, 0, 0, 0, 0, 0, 0, 0};

    int2 e0 = csr[beg], e1 = csr[beg + 1], e2 = csr[beg + 2], e3 = csr[beg + 3];
    int j = beg;
    while (j + 4 <= end) {
        uint4 x0 = ego_in[(size_t)e0.x * 8 + l];
        uint4 x1 = ego_in[(size_t)e1.x * 8 + l];
        uint4 x2 = ego_in[(size_t)e2.x * 8 + l];
        uint4 x3 = ego_in[(size_t)e3.x * 8 + l];
        int2 n0 = csr[j + 4], n1 = csr[j + 5], n2 = csr[j + 6], n3 = csr[j + 7];
        fma8(a0, __int_as_float(e0.y), x0);
        fma8(a1, __int_as_float(e1.y), x1);
        fma8(a0, __int_as_float(e2.y), x2);
        fma8(a1, __int_as_float(e3.y), x3);
        e0 = n0; e1 = n1; e2 = n2; e3 = n3;
        j += 4;
    }
    int rem = end - j;  // 0..3
    if (rem > 0) fma8(a0, __int_as_float(e0.y), ego_in[(size_t)e0.x * 8 + l]);
    if (rem > 1) fma8(a1, __int_as_float(e1.y), ego_in[(size_t)e1.x * 8 + l]);
    if (rem > 2) fma8(a0, __int_as_float(e2.y), ego_in[(size_t)e2.x * 8 + l]);

    float acc[8];
#pragma unroll
    for (int k = 0; k < 8; ++k) acc[k] = a0[k] + a1[k];

    if (!FINAL) {
        uint4 r;
        r.x = pack2(acc[0], acc[1]); r.y = pack2(acc[2], acc[3]);
        r.z = pack2(acc[4], acc[5]); r.w = pack2(acc[6], acc[7]);
        ego_out[(size_t)node * 8 + l] = r;
    } else {
        uint4 a = egoA[(size_t)node * 8 + l];
        uint4 b = egoB[(size_t)node * 8 + l];
        const float s = 1.0f / 3.0f;
        float4 o0, o1;
        o0.x = (blo(a.x) + blo(b.x) + acc[0]) * s;
        o0.y = (bhi(a.x) + bhi(b.x) + acc[1]) * s;
        o0.z = (blo(a.y) + blo(b.y) + acc[2]) * s;
        o0.w = (bhi(a.y) + bhi(b.y) + acc[3]) * s;
        o1.x = (blo(a.z) + blo(b.z) + acc[4]) * s;
        o1.y = (bhi(a.z) + bhi(b.z) + acc[5]) * s;
        o1.z = (blo(a.w) + blo(b.w) + acc[6]) * s;
        o1.w = (bhi(a.w) + bhi(b.w) + acc[7]) * s;
        size_t ob = (size_t)node * 16 + 2 * l;
        out[ob]     = o0;
        out[ob + 1] = o1;
    }
}

static inline size_t align_up(size_t x, size_t a) { return (x + a - 1) & ~(a - 1); }

extern "C" void kernel_launch(void* const* d_in, const int* in_sizes, int n_in,
                              void* d_out, int out_size, void* d_ws, size_t ws_size,
                              hipStream_t stream) {
    const float* user_emb  = (const float*)d_in[0];
    const float* item_emb  = (const float*)d_in[1];
    const int*   edge_src  = (const int*)d_in[2];
    const int*   edge_dst  = (const int*)d_in[3];
    const float* edge_vals = (const float*)d_in[4];
    const int    nE        = in_sizes[2];  // 2E = 1.2M

    float* out = (float*)d_out;
    const size_t nd = (size_t)N_NODES * D_DIM;

    const int NB_B = (nE + CHUNK - 1) / CHUNK;  // 293

    // ---- ws layout ----
    size_t off = 0;
    char* base = (char*)d_ws;
    int2*  csr     = (int2*)(base + off);  off = align_up(off + (size_t)(nE + 4) * sizeof(int2), 256);
    int*   row_ptr = (int*)(base + off);   off = align_up(off + (size_t)(N_NODES + 1) * 4, 256);
    uint2* tmp     = (uint2*)(base + off); off = align_up(off + (size_t)nE * sizeof(uint2), 256);
    int*   bCnt    = (int*)(base + off);   off = align_up(off + (size_t)NBKT * 4, 256);
    int*   bCursor = (int*)(base + off);   off = align_up(off + (size_t)NBKT * 4, 256);
    int*   bBase   = (int*)(base + off);   off = align_up(off + (size_t)(NBKT + 1) * 4, 256);
    uint4* ego0    = (uint4*)(base + off); off = align_up(off + (size_t)N_NODES * 128, 256);
    uint4* ego_a   = (uint4*)(base + off); off = align_up(off + (size_t)N_NODES * 128, 256);
    uint4* ego_b   = (uint4*)(base + off); off = align_up(off + (size_t)N_NODES * 128, 256);

    const int block = 256;
    const int n4  = (int)(nd / 4);
    const int n4u = U_CNT * D_DIM / 4;

    // ---- CSR build: hist -> scan -> reserve+scatter -> fine sort ----
    hipMemsetAsync(bCnt, 0, 2 * align_up((size_t)NBKT * 4, 256), stream);  // bCnt + bCursor
    bucket_hist<<<NB_B, block, 0, stream>>>(edge_dst, bCnt, nE,
        (const float4*)user_emb, (const float4*)item_emb, (uint2*)ego0, n4u, n4);
    scan586<<<1, 1024, 0, stream>>>(bCnt, bBase, nE);
    bucket_scatter<<<NB_B, block, 0, stream>>>(edge_src, edge_dst, edge_vals,
                                               bBase, bCursor, tmp, nE);
    bucket_build<<<NBKT, block, 0, stream>>>(bBase, tmp, csr, row_ptr, nE);

    // ---- 3 SpMM layers (bf16 gather, 8 lanes/node, x4 unroll) ----
    const size_t threads = (size_t)N_NODES * 8;
    const int spmm_grid = (int)((threads + block - 1) / block);

    lgcn_spmm<0><<<spmm_grid, block, 0, stream>>>(
        row_ptr, csr, ego0, ego_a, nullptr, nullptr, nullptr);
    lgcn_spmm<0><<<spmm_grid, block, 0, stream>>>(
        row_ptr, csr, ego_a, ego_b, nullptr, nullptr, nullptr);
    lgcn_spmm<1><<<spmm_grid, block, 0, stream>>>(
        row_ptr, csr, ego_b, nullptr, ego_a, ego_b, (float4*)out);
}